// Round 2
// baseline (882.285 us; speedup 1.0000x reference)
//
#include <hip/hip_runtime.h>
#include <stdint.h>

#define NH 8
#define HD 48
#define CC 384
#define NN 4096

typedef short short8 __attribute__((ext_vector_type(8)));
typedef float floatx4 __attribute__((ext_vector_type(4)));

__device__ inline unsigned short f32_to_bf16_bits(float f) {
    uint32_t u = __builtin_bit_cast(uint32_t, f);
    u = (u + 0x7FFFu + ((u >> 16) & 1u)) >> 16;
    return (unsigned short)u;
}
__device__ inline float bf16_bits_to_f32(unsigned short h) {
    return __builtin_bit_cast(float, ((uint32_t)h) << 16);
}
__device__ inline short8 load8(const unsigned short* p) {
    return *reinterpret_cast<const short8*>(p);
}

// ---------------- dtype detector ----------------
// bf16 N(0,1) data: exponent field of every uint16 is < 0x90 (|v| <= ~6).
// f32 data: low-half uint16s are uniform-random -> ~9% have exp >= 0xE8.
__global__ void k_detect(const unsigned short* __restrict__ x, int* __restrict__ flag) {
    __shared__ int cnt;
    if (threadIdx.x == 0) cnt = 0;
    __syncthreads();
    int c = 0;
    for (int i = threadIdx.x; i < 16384; i += 256) {
        unsigned e = (x[i] >> 7) & 0xFFu;
        if (e >= 0xE8u) ++c;
    }
    atomicAdd(&cnt, c);
    __syncthreads();
    if (threadIdx.x == 0) *flag = (cnt >= 16) ? 1 : 0;
}

// ---------------- input normalizer: anything -> bf16 ----------------
__global__ __launch_bounds__(256) void k_convert(
    const void* __restrict__ src, unsigned short* __restrict__ dst,
    int n8, const int* __restrict__ flagp)
{
    int i = blockIdx.x * 256 + threadIdx.x;
    if (i >= n8) return;
    if (*flagp) {
        const float* s = (const float*)src + (size_t)i * 8;
        unsigned short tmp[8];
        #pragma unroll
        for (int j = 0; j < 8; ++j) tmp[j] = f32_to_bf16_bits(s[j]);
        *reinterpret_cast<short8*>(dst + (size_t)i * 8) = *reinterpret_cast<short8*>(tmp);
    } else {
        *reinterpret_cast<uint4*>(dst + (size_t)i * 8) =
            *((const uint4*)src + i);
    }
}

// ---------------- Kernel A: QKV GEMM ----------------
__global__ __launch_bounds__(256) void k_qkv(
    const unsigned short* __restrict__ x,      // [B][C][N] bf16
    const unsigned short* __restrict__ w,      // [3C][C] bf16
    unsigned short* __restrict__ Qb,           // [B][NH][N][HD]
    unsigned short* __restrict__ Kb,
    unsigned short* __restrict__ Vb)
{
    __shared__ unsigned short xT[64][72];
    const int bx = blockIdx.x;
    const int ft = bx % 18;
    const int nt = (bx / 18) & 63;
    const int b  = bx / (18 * 64);
    const int f0 = ft * 64;
    const int n0 = nt * 64;
    const int tid  = threadIdx.x;
    const int wid  = tid >> 6;
    const int lane = tid & 63;
    const int l15  = lane & 15;
    const int quad = lane >> 4;
    const int m0   = wid * 16;

    floatx4 acc[4] = {};

    for (int kc = 0; kc < 6; ++kc) {
        __syncthreads();
        #pragma unroll
        for (int it = 0; it < 2; ++it) {
            int vi  = tid + it * 256;
            int cl  = vi >> 3;
            int seg = vi & 7;
            const unsigned short* src = x + (size_t)(b * CC + kc * 64 + cl) * NN + n0 + seg * 8;
            uint4 val = *reinterpret_cast<const uint4*>(src);
            uint32_t vv[4] = {val.x, val.y, val.z, val.w};
            #pragma unroll
            for (int j = 0; j < 4; ++j) {
                xT[seg * 8 + 2 * j + 0][cl] = (unsigned short)(vv[j] & 0xFFFFu);
                xT[seg * 8 + 2 * j + 1][cl] = (unsigned short)(vv[j] >> 16);
            }
        }
        __syncthreads();
        #pragma unroll
        for (int ks = 0; ks < 2; ++ks) {
            short8 a = load8(&xT[m0 + l15][ks * 32 + quad * 8]);
            #pragma unroll
            for (int t = 0; t < 4; ++t) {
                const unsigned short* wp =
                    w + (size_t)(f0 + t * 16 + l15) * CC + kc * 64 + ks * 32 + quad * 8;
                acc[t] = __builtin_amdgcn_mfma_f32_16x16x32_bf16(a, load8(wp), acc[t], 0, 0, 0);
            }
        }
    }
    #pragma unroll
    for (int t = 0; t < 4; ++t) {
        int f    = f0 + t * 16 + l15;
        int kind = f / CC;
        int fr   = f - kind * CC;
        int h    = fr / HD;
        int d    = fr - h * HD;
        unsigned short* dst = (kind == 0) ? Qb : ((kind == 1) ? Kb : Vb);
        #pragma unroll
        for (int r = 0; r < 4; ++r) {
            int tok = n0 + m0 + quad * 4 + r;
            dst[((size_t)(b * NH + h) * NN + tok) * HD + d] = f32_to_bf16_bits(acc[t][r]);
        }
    }
}

// ---------------- Kernel B: block-local attention ----------------
__global__ __launch_bounds__(256) void k_attn(
    const unsigned short* __restrict__ Qb,
    const unsigned short* __restrict__ Kb,
    const unsigned short* __restrict__ Vb,
    unsigned short* __restrict__ AO)           // [B][N][C]
{
    __shared__ unsigned short ql[64][64];
    __shared__ unsigned short kl[64][64];
    __shared__ unsigned short vt[48][72];
    __shared__ float          sc[64][66];
    __shared__ unsigned short pl[64][72];

    const int bx = blockIdx.x;
    const int cn = bx & 63;
    const int h  = (bx >> 6) & 7;
    const int b  = bx >> 9;
    const int n0 = cn * 64;
    const int tid  = threadIdx.x;
    const int wid  = tid >> 6;
    const int lane = tid & 63;
    const int l15  = lane & 15;
    const int quad = lane >> 4;
    const int m0   = wid * 16;

    const size_t base = ((size_t)(b * NH + h) * NN + n0) * HD;

    for (int v = tid; v < 64 * 12; v += 256) {
        int row = v / 12, seg = v - row * 12;
        *reinterpret_cast<uint2*>(&ql[row][seg * 4]) =
            *reinterpret_cast<const uint2*>(Qb + base + row * HD + seg * 4);
        *reinterpret_cast<uint2*>(&kl[row][seg * 4]) =
            *reinterpret_cast<const uint2*>(Kb + base + row * HD + seg * 4);
    }
    for (int v = tid; v < 64 * 16; v += 256) {
        int row = v >> 4, col = 48 + (v & 15);
        ql[row][col] = 0;
        kl[row][col] = 0;
    }
    for (int v = tid; v < 64 * HD; v += 256) {
        int row = v / HD, d = v - row * HD;
        vt[d][row] = Vb[base + v];
    }
    __syncthreads();

    const float scale = 0.14433756729740643f;  // 48^-0.5
    #pragma unroll
    for (int t = 0; t < 4; ++t) {
        floatx4 sacc = {};
        #pragma unroll
        for (int ks = 0; ks < 2; ++ks) {
            short8 a  = load8(&ql[m0 + l15][ks * 32 + quad * 8]);
            short8 bb = load8(&kl[t * 16 + l15][ks * 32 + quad * 8]);
            sacc = __builtin_amdgcn_mfma_f32_16x16x32_bf16(a, bb, sacc, 0, 0, 0);
        }
        #pragma unroll
        for (int r = 0; r < 4; ++r)
            sc[m0 + quad * 4 + r][t * 16 + l15] = sacc[r] * scale;
    }
    __syncthreads();

    if (tid < 64) {
        int row = tid;
        float m = -1e30f;
        for (int j = 0; j < 64; ++j) m = fmaxf(m, sc[row][j]);
        float s = 0.f;
        for (int j = 0; j < 64; ++j) { float e = __expf(sc[row][j] - m); sc[row][j] = e; s += e; }
        float inv = 1.0f / s;
        for (int j = 0; j < 64; ++j) pl[row][j] = f32_to_bf16_bits(sc[row][j] * inv);
    }
    __syncthreads();

    #pragma unroll
    for (int t = 0; t < 3; ++t) {
        floatx4 oacc = {};
        #pragma unroll
        for (int ks = 0; ks < 2; ++ks) {
            short8 a  = load8(&pl[m0 + l15][ks * 32 + quad * 8]);
            short8 bb = load8(&vt[t * 16 + l15][ks * 32 + quad * 8]);
            oacc = __builtin_amdgcn_mfma_f32_16x16x32_bf16(a, bb, oacc, 0, 0, 0);
        }
        #pragma unroll
        for (int r = 0; r < 4; ++r) {
            int tok = n0 + m0 + quad * 4 + r;
            AO[((size_t)b * NN + tok) * CC + h * HD + t * 16 + l15] =
                f32_to_bf16_bits(oacc[r]);
        }
    }
}

// ---------------- Kernel C: output projection ----------------
__global__ __launch_bounds__(256) void k_proj(
    const unsigned short* __restrict__ AO,     // [B][N][C] bf16
    const unsigned short* __restrict__ w,      // [C][C] bf16
    const unsigned short* __restrict__ bias,   // [C] bf16
    void* __restrict__ outv,                   // [B][C][N] bf16 or f32
    const int* __restrict__ flagp)
{
    __shared__ unsigned short ot[64][72];
    const int bx = blockIdx.x;
    const int ct = bx % 6;
    const int nt = (bx / 6) & 63;
    const int b  = bx / (6 * 64);
    const int c0 = ct * 64;
    const int n0 = nt * 64;
    const int tid  = threadIdx.x;
    const int wid  = tid >> 6;
    const int lane = tid & 63;
    const int l15  = lane & 15;
    const int quad = lane >> 4;

    floatx4 acc[4] = {};
    const unsigned short* ap0 = AO + ((size_t)b * NN + n0 + wid * 16 + l15) * CC + quad * 8;
    const unsigned short* wp0 = w + (size_t)(c0 + l15) * CC + quad * 8;
    #pragma unroll 4
    for (int ks = 0; ks < 12; ++ks) {
        short8 a = load8(ap0 + ks * 32);
        #pragma unroll
        for (int t = 0; t < 4; ++t) {
            acc[t] = __builtin_amdgcn_mfma_f32_16x16x32_bf16(
                a, load8(wp0 + (size_t)t * 16 * CC + ks * 32), acc[t], 0, 0, 0);
        }
    }
    #pragma unroll
    for (int t = 0; t < 4; ++t) {
        int cl   = t * 16 + l15;
        float bv = bf16_bits_to_f32(bias[c0 + cl]);
        #pragma unroll
        for (int r = 0; r < 4; ++r)
            ot[cl][wid * 16 + quad * 4 + r] = f32_to_bf16_bits(acc[t][r] + bv);
    }
    __syncthreads();
    if (*flagp) {
        float* out = (float*)outv;
        for (int v = tid; v < 512; v += 256) {
            int row = v >> 3, seg = v & 7;
            float* dst = out + (size_t)(b * CC + c0 + row) * NN + n0 + seg * 8;
            float4 f0, f1;
            f0.x = bf16_bits_to_f32(ot[row][seg * 8 + 0]);
            f0.y = bf16_bits_to_f32(ot[row][seg * 8 + 1]);
            f0.z = bf16_bits_to_f32(ot[row][seg * 8 + 2]);
            f0.w = bf16_bits_to_f32(ot[row][seg * 8 + 3]);
            f1.x = bf16_bits_to_f32(ot[row][seg * 8 + 4]);
            f1.y = bf16_bits_to_f32(ot[row][seg * 8 + 5]);
            f1.z = bf16_bits_to_f32(ot[row][seg * 8 + 6]);
            f1.w = bf16_bits_to_f32(ot[row][seg * 8 + 7]);
            *reinterpret_cast<float4*>(dst + 0) = f0;
            *reinterpret_cast<float4*>(dst + 4) = f1;
        }
    } else {
        unsigned short* out = (unsigned short*)outv;
        for (int v = tid; v < 512; v += 256) {
            int row = v >> 3, seg = v & 7;
            *reinterpret_cast<short8*>(out + (size_t)(b * CC + c0 + row) * NN + n0 + seg * 8) =
                *reinterpret_cast<const short8*>(&ot[row][seg * 8]);
        }
    }
}

extern "C" void kernel_launch(void* const* d_in, const int* in_sizes, int n_in,
                              void* d_out, int out_size, void* d_ws, size_t ws_size,
                              hipStream_t stream) {
    const size_t nX  = (size_t)16 * CC * NN;        // 25,165,824
    const size_t nW1 = (size_t)3 * CC * CC;         // 442,368
    const size_t nW2 = (size_t)CC * CC;             // 147,456
    const size_t nB  = CC;                          // 384
    const size_t per = (size_t)16 * NH * NN * HD;   // 25,165,824

    unsigned short* xb   = (unsigned short*)d_ws;
    unsigned short* w1b  = xb  + nX;
    unsigned short* w2b  = w1b + nW1;
    unsigned short* bb   = w2b + nW2;
    unsigned short* Qb   = bb  + nB;
    unsigned short* Kb   = Qb  + per;
    unsigned short* Vb   = Kb  + per;
    unsigned short* AO   = Vb  + per;
    int*            flag = (int*)(AO + per);

    k_detect<<<dim3(1), dim3(256), 0, stream>>>((const unsigned short*)d_in[0], flag);

    k_convert<<<dim3((int)(nX  / 8 + 255) / 256), dim3(256), 0, stream>>>(d_in[0], xb,  (int)(nX  / 8), flag);
    k_convert<<<dim3((int)(nW1 / 8 + 255) / 256), dim3(256), 0, stream>>>(d_in[1], w1b, (int)(nW1 / 8), flag);
    k_convert<<<dim3((int)(nW2 / 8 + 255) / 256), dim3(256), 0, stream>>>(d_in[2], w2b, (int)(nW2 / 8), flag);
    k_convert<<<dim3((int)(nB  / 8 + 255) / 256), dim3(256), 0, stream>>>(d_in[3], bb,  (int)(nB  / 8), flag);

    k_qkv <<<dim3(16 * 64 * 18), dim3(256), 0, stream>>>(xb, w1b, Qb, Kb, Vb);
    k_attn<<<dim3(16 * 8 * 64),  dim3(256), 0, stream>>>(Qb, Kb, Vb, AO);
    k_proj<<<dim3(16 * 64 * 6),  dim3(256), 0, stream>>>(AO, w2b, bb, d_out, flag);
}

// Round 3
// 393.075 us; speedup vs baseline: 2.2446x; 2.2446x over previous
//
#include <hip/hip_runtime.h>
#include <stdint.h>

#define NH 8
#define HD 48
#define CC 384
#define NN 4096
#define CK 384

typedef short short8 __attribute__((ext_vector_type(8)));
typedef float floatx4 __attribute__((ext_vector_type(4)));

__device__ inline unsigned short f32_to_bf16_bits(float f) {
    uint32_t u = __builtin_bit_cast(uint32_t, f);
    u = (u + 0x7FFFu + ((u >> 16) & 1u)) >> 16;
    return (unsigned short)u;
}
__device__ inline short8 load8(const unsigned short* p) {
    return *reinterpret_cast<const short8*>(p);
}
typedef __attribute__((address_space(1))) const void gvoid_t;
typedef __attribute__((address_space(3))) void lvoid_t;
__device__ inline void async16(const unsigned short* g, unsigned short* l) {
    __builtin_amdgcn_global_load_lds((gvoid_t*)g, (lvoid_t*)l, 16, 0, 0);
}

// ---------------- weight convert f32 -> bf16 ----------------
__global__ __launch_bounds__(256) void k_cvt(
    const float* __restrict__ src, unsigned short* __restrict__ dst, int n8)
{
    int i = blockIdx.x * 256 + threadIdx.x;
    if (i >= n8) return;
    const float* s = src + (size_t)i * 8;
    unsigned short t[8];
    #pragma unroll
    for (int j = 0; j < 8; ++j) t[j] = f32_to_bf16_bits(s[j]);
    *reinterpret_cast<short8*>(dst + (size_t)i * 8) = *reinterpret_cast<short8*>(t);
}

// ---------------- x transpose: [B][C][N] f32 -> [B*N][C] bf16 ----------------
__global__ __launch_bounds__(256) void k_tr(
    const float* __restrict__ x, unsigned short* __restrict__ xT)
{
    __shared__ unsigned short tile[64][72];
    int bx = blockIdx.x;
    int nt = bx & 63; int rest = bx >> 6; int ct = rest % 6; int b = rest / 6;
    int c0 = ct * 64, n0 = nt * 64;
    int t = threadIdx.x;
    int nl = t & 63, w = t >> 6;
    const float* xb = x + (size_t)b * CC * NN;
    #pragma unroll
    for (int i = 0; i < 4; ++i) {
        int cl = w * 16 + i * 4;
        unsigned short u[4];
        #pragma unroll
        for (int j = 0; j < 4; ++j)
            u[j] = f32_to_bf16_bits(xb[(size_t)(c0 + cl + j) * NN + n0 + nl]);
        *reinterpret_cast<uint2*>(&tile[nl][cl]) = *reinterpret_cast<uint2*>(u);
    }
    __syncthreads();
    #pragma unroll
    for (int it = 0; it < 2; ++it) {
        int v = it * 256 + t;
        int row = v >> 3, seg = v & 7;
        *reinterpret_cast<short8*>(xT + ((size_t)b * NN + n0 + row) * CK + c0 + seg * 8) =
            load8(&tile[row][seg * 8]);
    }
}

// ---------------- QKV GEMM (m97-style 128x128x64) ----------------
// A = xT [65536][384], W = w1 [1152][384]; out: QK [tok][768] + Vt [B][8][48][4096]
__global__ __launch_bounds__(256) void k_qkv(
    const unsigned short* __restrict__ A,
    const unsigned short* __restrict__ W,
    unsigned short* __restrict__ QK,
    unsigned short* __restrict__ Vt)
{
    __shared__ unsigned short smem[17408];
    unsigned short* As = smem;
    unsigned short* Ws = smem + 8192;
    int bx = blockIdx.x;
    int tf = bx % 9, tm = bx / 9;
    int m0 = tm * 128, f0 = tf * 128;
    int tid = threadIdx.x, wid = tid >> 6, lane = tid & 63;
    int l15 = lane & 15, quad = lane >> 4;
    int wm = wid & 1, wn = wid >> 1;

    const unsigned short* Ab = A + (size_t)m0 * CK;
    const unsigned short* Wb = W + (size_t)f0 * CK;

    floatx4 acc[4][4] = {};

    for (int kk = 0; kk < 6; ++kk) {
        int k0 = kk * 64;
        #pragma unroll
        for (int i = 0; i < 4; ++i) {
            int c = i * 256 + tid;
            async16(Ab + (size_t)(c >> 3) * CK + k0 + (c & 7) * 8, As + (i * 256 + wid * 64) * 8);
            async16(Wb + (size_t)(c >> 3) * CK + k0 + (c & 7) * 8, Ws + (i * 256 + wid * 64) * 8);
        }
        __syncthreads();
        #pragma unroll
        for (int ks = 0; ks < 2; ++ks) {
            short8 a[4], bf[4];
            #pragma unroll
            for (int i = 0; i < 4; ++i)
                a[i] = load8(As + (wm * 64 + i * 16 + l15) * 64 + ks * 32 + quad * 8);
            #pragma unroll
            for (int j = 0; j < 4; ++j)
                bf[j] = load8(Ws + (wn * 64 + j * 16 + l15) * 64 + ks * 32 + quad * 8);
            #pragma unroll
            for (int i = 0; i < 4; ++i)
                #pragma unroll
                for (int j = 0; j < 4; ++j)
                    acc[i][j] = __builtin_amdgcn_mfma_f32_16x16x32_bf16(a[i], bf[j], acc[i][j], 0, 0, 0);
        }
        __syncthreads();
    }

    int b = m0 >> 12, nb = m0 & 4095;
    if (tf < 6) {
        #pragma unroll
        for (int i = 0; i < 4; ++i)
            #pragma unroll
            for (int j = 0; j < 4; ++j)
                #pragma unroll
                for (int r = 0; r < 4; ++r)
                    smem[(wm * 64 + i * 16 + quad * 4 + r) * 128 + wn * 64 + j * 16 + l15] =
                        f32_to_bf16_bits(acc[i][j][r]);
        __syncthreads();
        #pragma unroll
        for (int it = 0; it < 8; ++it) {
            int c = it * 256 + tid;
            int row = c >> 4, seg = c & 15;
            *reinterpret_cast<short8*>(QK + (size_t)(m0 + row) * 768 + f0 + seg * 8) =
                load8(smem + row * 128 + seg * 8);
        }
    } else {
        #pragma unroll
        for (int i = 0; i < 4; ++i)
            #pragma unroll
            for (int j = 0; j < 4; ++j)
                #pragma unroll
                for (int r = 0; r < 4; ++r)
                    smem[(wn * 64 + j * 16 + l15) * 136 + wm * 64 + i * 16 + quad * 4 + r] =
                        f32_to_bf16_bits(acc[i][j][r]);
        __syncthreads();
        int fvb = (tf - 6) * 128;
        #pragma unroll
        for (int it = 0; it < 8; ++it) {
            int c = it * 256 + tid;
            int fl = c >> 4, seg = c & 15;
            int fv = fvb + fl;
            int h = fv / 48, d = fv - h * 48;
            *reinterpret_cast<short8*>(Vt + (((size_t)(b * 8 + h) * 48 + d) << 12) + nb + seg * 8) =
                load8(smem + fl * 136 + seg * 8);
        }
    }
}

// ---------------- block-local attention ----------------
__global__ __launch_bounds__(256) void k_attn(
    const unsigned short* __restrict__ QK,     // [B*N][768]
    const unsigned short* __restrict__ Vt,     // [B][8][48][4096]
    unsigned short* __restrict__ AO)           // [B*N][384]
{
    __shared__ unsigned short ql[64][64];
    __shared__ unsigned short kl[64][64];
    __shared__ unsigned short vt[48][72];
    __shared__ float          sc[64][66];
    __shared__ unsigned short pl[64][72];

    int bx = blockIdx.x;
    int cn = bx & 63, h = (bx >> 6) & 7, b = bx >> 9;
    int n0 = cn * 64;
    int tid = threadIdx.x, wid = tid >> 6, lane = tid & 63;
    int l15 = lane & 15, quad = lane >> 4;
    int m0w = wid * 16;
    int h48 = h * 48;
    size_t b4 = (size_t)b * NN + n0;

    // stage Q,K rows (6 x 16B chunks per row per matrix)
    for (int v = tid; v < 768; v += 256) {
        int mat = v / 384;
        int idx = v - mat * 384;
        int rr = idx / 6, seg = idx - rr * 6;
        uint4 val = *reinterpret_cast<const uint4*>(QK + (b4 + rr) * 768 + mat * 384 + h48 + seg * 8);
        unsigned short* dst = mat ? &kl[rr][seg * 8] : &ql[rr][seg * 8];
        *reinterpret_cast<uint4*>(dst) = val;
    }
    // zero-pad d = 48..63
    {
        short8 z = {};
        int v = tid;
        if (v < 256) {
            int mat = v >> 7, rr = (v >> 1) & 63, half = v & 1;
            unsigned short* dst = mat ? &kl[rr][48 + half * 8] : &ql[rr][48 + half * 8];
            *reinterpret_cast<short8*>(dst) = z;
        }
    }
    // stage V^T rows (48 d-rows x 8 chunks)
    for (int v = tid; v < 384; v += 256) {
        int d = v >> 3, seg = v & 7;
        *reinterpret_cast<uint4*>(&vt[d][seg * 8]) =
            *reinterpret_cast<const uint4*>(Vt + (((size_t)(b * 8 + h) * 48 + d) << 12) + n0 + seg * 8);
    }
    __syncthreads();

    const float scale = 0.14433756729740643f;  // 48^-0.5
    #pragma unroll
    for (int t = 0; t < 4; ++t) {
        floatx4 sacc = {};
        #pragma unroll
        for (int ks = 0; ks < 2; ++ks) {
            short8 a  = load8(&ql[m0w + l15][ks * 32 + quad * 8]);
            short8 bb = load8(&kl[t * 16 + l15][ks * 32 + quad * 8]);
            sacc = __builtin_amdgcn_mfma_f32_16x16x32_bf16(a, bb, sacc, 0, 0, 0);
        }
        #pragma unroll
        for (int r = 0; r < 4; ++r)
            sc[m0w + quad * 4 + r][t * 16 + l15] = sacc[r] * scale;
    }
    __syncthreads();

    // softmax: 64 rows, wave w owns rows w*16..+16, quad owns 16 cols
    {
        int row = m0w + l15;
        int jb  = quad * 16;
        float ev[16];
        #pragma unroll
        for (int jj = 0; jj < 16; ++jj) ev[jj] = sc[row][jb + jj];
        float m = ev[0];
        #pragma unroll
        for (int jj = 1; jj < 16; ++jj) m = fmaxf(m, ev[jj]);
        m = fmaxf(m, __shfl_xor(m, 16));
        m = fmaxf(m, __shfl_xor(m, 32));
        float s = 0.f;
        #pragma unroll
        for (int jj = 0; jj < 16; ++jj) { ev[jj] = __expf(ev[jj] - m); s += ev[jj]; }
        s += __shfl_xor(s, 16);
        s += __shfl_xor(s, 32);
        float inv = 1.0f / s;
        #pragma unroll
        for (int jj = 0; jj < 16; ++jj) pl[row][jb + jj] = f32_to_bf16_bits(ev[jj] * inv);
    }
    __syncthreads();

    // PV: A = pl [q][ki], B = vt [d][ki]; O tile staged into kl (free now)
    #pragma unroll
    for (int t = 0; t < 3; ++t) {
        floatx4 oacc = {};
        #pragma unroll
        for (int ks = 0; ks < 2; ++ks) {
            short8 a  = load8(&pl[m0w + l15][ks * 32 + quad * 8]);
            short8 bb = load8(&vt[t * 16 + l15][ks * 32 + quad * 8]);
            oacc = __builtin_amdgcn_mfma_f32_16x16x32_bf16(a, bb, oacc, 0, 0, 0);
        }
        #pragma unroll
        for (int r = 0; r < 4; ++r)
            kl[m0w + quad * 4 + r][t * 16 + l15] = f32_to_bf16_bits(oacc[r]);
    }
    __syncthreads();

    for (int v = tid; v < 384; v += 256) {
        int rr = v / 6, seg = v - rr * 6;
        *reinterpret_cast<short8*>(AO + (b4 + rr) * CC + h48 + seg * 8) =
            load8(&kl[rr][seg * 8]);
    }
}

// ---------------- proj GEMM (m97-style) + bias + transpose-store f32 ----------------
__global__ __launch_bounds__(256) void k_proj(
    const unsigned short* __restrict__ A,      // AO [65536][384]
    const unsigned short* __restrict__ W,      // w2 [384][384]
    const float* __restrict__ bias,            // [384] f32
    float* __restrict__ out)                   // [B][C][N] f32
{
    __shared__ unsigned short smem[17408];
    unsigned short* As = smem;
    unsigned short* Ws = smem + 8192;
    float* fs = (float*)smem;                  // [64][132] f32 staging
    int bx = blockIdx.x;
    int tf = bx % 3, tm = bx / 3;
    int m0 = tm * 128, f0 = tf * 128;
    int tid = threadIdx.x, wid = tid >> 6, lane = tid & 63;
    int l15 = lane & 15, quad = lane >> 4;
    int wm = wid & 1, wn = wid >> 1;

    const unsigned short* Ab = A + (size_t)m0 * CK;
    const unsigned short* Wb = W + (size_t)f0 * CK;

    floatx4 acc[4][4] = {};

    for (int kk = 0; kk < 6; ++kk) {
        int k0 = kk * 64;
        #pragma unroll
        for (int i = 0; i < 4; ++i) {
            int c = i * 256 + tid;
            async16(Ab + (size_t)(c >> 3) * CK + k0 + (c & 7) * 8, As + (i * 256 + wid * 64) * 8);
            async16(Wb + (size_t)(c >> 3) * CK + k0 + (c & 7) * 8, Ws + (i * 256 + wid * 64) * 8);
        }
        __syncthreads();
        #pragma unroll
        for (int ks = 0; ks < 2; ++ks) {
            short8 a[4], bf[4];
            #pragma unroll
            for (int i = 0; i < 4; ++i)
                a[i] = load8(As + (wm * 64 + i * 16 + l15) * 64 + ks * 32 + quad * 8);
            #pragma unroll
            for (int j = 0; j < 4; ++j)
                bf[j] = load8(Ws + (wn * 64 + j * 16 + l15) * 64 + ks * 32 + quad * 8);
            #pragma unroll
            for (int i = 0; i < 4; ++i)
                #pragma unroll
                for (int j = 0; j < 4; ++j)
                    acc[i][j] = __builtin_amdgcn_mfma_f32_16x16x32_bf16(a[i], bf[j], acc[i][j], 0, 0, 0);
        }
        __syncthreads();
    }

    int b = m0 >> 12, nb = m0 & 4095;
    // two halves of 64 couts each, f32 transposed staging [cout][tok] ld 132
    #pragma unroll
    for (int hh = 0; hh < 2; ++hh) {
        if (wn == hh) {
            #pragma unroll
            for (int j = 0; j < 4; ++j) {
                float bv = bias[f0 + hh * 64 + j * 16 + l15];
                #pragma unroll
                for (int i = 0; i < 4; ++i)
                    #pragma unroll
                    for (int r = 0; r < 4; ++r)
                        fs[(j * 16 + l15) * 132 + wm * 64 + i * 16 + quad * 4 + r] =
                            acc[i][j][r] + bv;
            }
        }
        __syncthreads();
        #pragma unroll
        for (int it = 0; it < 8; ++it) {
            int c = it * 256 + tid;
            int cl = c >> 5, seg = c & 31;
            *reinterpret_cast<float4*>(
                out + (((size_t)(b * CC + f0 + hh * 64 + cl)) << 12) + nb + seg * 4) =
                *reinterpret_cast<const float4*>(fs + cl * 132 + seg * 4);
        }
        __syncthreads();
    }
}

extern "C" void kernel_launch(void* const* d_in, const int* in_sizes, int n_in,
                              void* d_out, int out_size, void* d_ws, size_t ws_size,
                              hipStream_t stream) {
    const float* x      = (const float*)d_in[0];
    const float* qkv_w  = (const float*)d_in[1];
    const float* proj_w = (const float*)d_in[2];
    const float* proj_b = (const float*)d_in[3];
    float* out = (float*)d_out;

    const size_t nX  = (size_t)16 * CC * NN;     // 25,165,824
    const size_t nW1 = (size_t)3 * CC * CC;      // 442,368
    const size_t nW2 = (size_t)CC * CC;          // 147,456

    unsigned short* xT  = (unsigned short*)d_ws;
    unsigned short* w1b = xT  + nX;
    unsigned short* w2b = w1b + nW1;
    unsigned short* QK  = w2b + nW2;             // [B*N][768]
    unsigned short* Vt  = QK  + (size_t)16 * NN * 768;
    unsigned short* AO  = Vt  + (size_t)16 * 8 * 48 * NN;

    k_tr  <<<dim3(16 * 6 * 64), dim3(256), 0, stream>>>(x, xT);
    k_cvt <<<dim3((int)(nW1 / 8 + 255) / 256), dim3(256), 0, stream>>>(qkv_w, w1b, (int)(nW1 / 8));
    k_cvt <<<dim3((int)(nW2 / 8 + 255) / 256), dim3(256), 0, stream>>>(proj_w, w2b, (int)(nW2 / 8));

    k_qkv <<<dim3(512 * 9), dim3(256), 0, stream>>>(xT, w1b, QK, Vt);
    k_attn<<<dim3(16 * 8 * 64), dim3(256), 0, stream>>>(QK, Vt, AO);
    k_proj<<<dim3(512 * 3), dim3(256), 0, stream>>>(AO, w2b, proj_b, out);
}